// Round 9
// baseline (295.810 us; speedup 1.0000x reference)
//
#include <hip/hip_runtime.h>
#include <hip/hip_fp16.h>
#include <stdint.h>

// SymmetricContraction (MACE) on MI355X — symmetrized monomials, 2-kernel split.
//
// out[b,c,m] = sum_{a<=b<=cc} x_a x_b x_cc*T3 + sum_{a<=b} x_a x_b*T2 + sum_a x_a*T1
// Horner: out = sum_a x_a*( T1[a] + sum_{b>=a} x_b*( T2[ab] + sum_{cc>=b} x_cc*T3 ) )
// Irreps fused into 4 slots (0e | 1o m=0..2), stored fp16 (R8 validated precision).
//
// R9 (from counters):
//  - prep_sym ELIMINATED: build_fused symmetrizes on the fly (6 permuted
//    contiguous K-dots of U3.w per entry, wave-uniform loads) + node lists.
//    R3-R8 showed a stable ~120us of non-apply kernel time; prep is gone and
//    build is restructured, so whichever owned it is addressed/surfaced.
//  - sc_apply: fp16 table (b64 LDS reads, half the R6 coef bytes) but with
//    SCALAR fmaf(__half2float(h), x, acc) -> v_fma_mix_f32 (fpext folded as
//    operand modifier). R8's cvt+splat+pk path (20 VALU/entry, dep chains)
//    was the regression; this is 8 direct load->fma ops per entry.

#define BN 2048
#define CN 128
#define EN 10

#define NT3 816   // #sorted triples a<=b<=cc in [0,16)
#define NT2 136   // #sorted pairs a<=b
#define NTT (NT3 + NT2 + 16)   // 968 fused table entries
#define K3_0 23
#define K3_1 33
#define K2_0 4
#define K2_1 5

// ---- main-path ws layout ----
// ints [0, EN*BN): node lists; [EN*BN, EN*BN+EN): counts; then fp16 table.
#define TALL2F 20490   // float offset of table ( (EN*BN+EN+1)&~1 ), byte 81960, 8B-aligned
#define WS2_NEED_BYTES ((size_t)TALL2F*4 + (size_t)EN*CN*NTT*8)

// ---- fallback-path ws layout (old, f32 sym regions) ----
#define U3S0_OFF 0
#define U3S1_OFF (K3_0*NT3)
#define U2S0_OFF (U3S1_OFF + 3*K3_1*NT3)
#define U2S1_OFF (U2S0_OFF + K2_0*NT2)
#define LISTS_OFF (U2S1_OFF + 3*K2_1*NT2)
#define CNT_OFF (LISTS_OFF + EN*BN)
#define WSF_NEED_BYTES ((size_t)(CNT_OFF + EN) * 4)
#define PREP_TOT (K3_0*NT3 + 3*K3_1*NT3 + K2_0*NT2 + 3*K2_1*NT2)
#define PREP_BLOCKS ((PREP_TOT + 255) / 256)

typedef float v2f __attribute__((ext_vector_type(2)));

static __device__ __forceinline__ uint2 pack_h4(float a0, float a1, float a2, float a3) {
    __half2 lo = __floats2half2_rn(a0, a1);
    __half2 hi = __floats2half2_rn(a2, a3);
    uint2 r;
    r.x = *reinterpret_cast<const unsigned int*>(&lo);
    r.y = *reinterpret_cast<const unsigned int*>(&hi);
    return r;
}

// accumulate one permutation's K-dots for a triple entry (all idx uniform)
static __device__ __forceinline__ void acc_perm3(
    const float* __restrict__ U3_0, const float* __restrict__ U3_1, int idx,
    const float (&w0)[K3_0], const float (&w1)[K3_1],
    float& s0, float& s1, float& s2, float& s3)
{
    const float* u0p = U3_0 + idx * K3_0;
#pragma unroll
    for (int k = 0; k < K3_0; ++k) s0 = fmaf(u0p[k], w0[k], s0);
    const float* u1p = U3_1 + (size_t)idx * K3_1;
#pragma unroll
    for (int k = 0; k < K3_1; ++k) {
        const float wv = w1[k];
        s1 = fmaf(u1p[k], wv, s1);
        s2 = fmaf(u1p[135168 + k], wv, s2);   // m=1: 4096*33
        s3 = fmaf(u1p[270336 + k], wv, s3);   // m=2
    }
}

// ---- fused: node lists + fp16 coefficient tables straight from U,W --------
// grid (122, EN): gx<121 -> 8-entry chunk of the table for (chunk, e), thread=c.
//                 gx==121 -> node list for element e.
__global__ __launch_bounds__(128) void build_fused(
    const float* __restrict__ U3_0, const float* __restrict__ U2_0, const float* __restrict__ U1_0,
    const float* __restrict__ U3_1, const float* __restrict__ U2_1, const float* __restrict__ U1_1,
    const float* __restrict__ W3_0, const float* __restrict__ W2_0, const float* __restrict__ W1_0,
    const float* __restrict__ W3_1, const float* __restrict__ W2_1, const float* __restrict__ W1_1,
    const float* __restrict__ yg, float* __restrict__ ws)
{
    const int gx = blockIdx.x, e = blockIdx.y, tid = threadIdx.x;
    if (gx == 121) {
        __shared__ int lcnt;
        if (tid == 0) lcnt = 0;
        __syncthreads();
        int* lists = (int*)ws;
        for (int b = tid; b < BN; b += 128) {
            if (yg[b * EN + e] > 0.5f) {
                int p = atomicAdd(&lcnt, 1);
                lists[e * BN + p] = b;
            }
        }
        __syncthreads();
        if (tid == 0) ((int*)ws)[EN * BN + e] = lcnt;
        return;
    }

    const int g0 = gx * 8;
    const int c = tid;
    uint2* out8 = (uint2*)(ws + TALL2F) + (size_t)(e * CN + c) * NTT;

    if (g0 < NT3) {
        float w0[K3_0], w1[K3_1];
#pragma unroll
        for (int k = 0; k < K3_0; ++k) w0[k] = W3_0[(e * K3_0 + k) * CN + c];
#pragma unroll
        for (int k = 0; k < K3_1; ++k) w1[k] = W3_1[(e * K3_1 + k) * CN + c];
#pragma unroll 1
        for (int j = 0; j < 8; ++j) {
            const int g = g0 + j;
            // unrank g -> (a<=b<=cc), lexicographic (matches sc_apply order)
            int a = 0, rem = g;
            while (rem >= ((16 - a) * (17 - a)) / 2) { rem -= ((16 - a) * (17 - a)) / 2; ++a; }
            int b = a;
            while (rem >= 16 - b) { rem -= 16 - b; ++b; }
            const int cc = b + rem;
            float s0 = 0.f, s1 = 0.f, s2 = 0.f, s3 = 0.f;
            acc_perm3(U3_0, U3_1, (a * 16 + b) * 16 + cc, w0, w1, s0, s1, s2, s3);
            acc_perm3(U3_0, U3_1, (a * 16 + cc) * 16 + b, w0, w1, s0, s1, s2, s3);
            acc_perm3(U3_0, U3_1, (b * 16 + a) * 16 + cc, w0, w1, s0, s1, s2, s3);
            acc_perm3(U3_0, U3_1, (b * 16 + cc) * 16 + a, w0, w1, s0, s1, s2, s3);
            acc_perm3(U3_0, U3_1, (cc * 16 + a) * 16 + b, w0, w1, s0, s1, s2, s3);
            acc_perm3(U3_0, U3_1, (cc * 16 + b) * 16 + a, w0, w1, s0, s1, s2, s3);
            const int eq = (a == b) + (b == cc);
            const float sc = (eq == 2) ? (1.f / 6.f) : (eq == 1) ? 0.5f : 1.f;
            out8[g] = pack_h4(s0 * sc, s1 * sc, s2 * sc, s3 * sc);
        }
    } else if (g0 < NT3 + NT2) {
        float w0[K2_0], w1[K2_1];
#pragma unroll
        for (int k = 0; k < K2_0; ++k) w0[k] = W2_0[(e * K2_0 + k) * CN + c];
#pragma unroll
        for (int k = 0; k < K2_1; ++k) w1[k] = W2_1[(e * K2_1 + k) * CN + c];
#pragma unroll 1
        for (int j = 0; j < 8; ++j) {
            const int g = g0 + j;
            int a = 0, rem = g - NT3;
            while (rem >= 16 - a) { rem -= 16 - a; ++a; }
            const int b = a + rem;
            float s0 = 0.f, s1 = 0.f, s2 = 0.f, s3 = 0.f;
#pragma unroll
            for (int p = 0; p < 2; ++p) {
                const int i = p ? b : a, jj = p ? a : b;
                const float* u0p = U2_0 + (i * 16 + jj) * K2_0;
#pragma unroll
                for (int k = 0; k < K2_0; ++k) s0 = fmaf(u0p[k], w0[k], s0);
                const float* u1p = U2_1 + (i * 16 + jj) * K2_1;
#pragma unroll
                for (int k = 0; k < K2_1; ++k) {
                    const float wv = w1[k];
                    s1 = fmaf(u1p[k], wv, s1);
                    s2 = fmaf(u1p[1280 + k], wv, s2);   // m=1: 256*5
                    s3 = fmaf(u1p[2560 + k], wv, s3);   // m=2
                }
            }
            const float sc = (a == b) ? 0.5f : 1.f;
            out8[g] = pack_h4(s0 * sc, s1 * sc, s2 * sc, s3 * sc);
        }
    } else {
        const float w10 = W1_0[e * CN + c];
        const float w11 = W1_1[e * CN + c];
#pragma unroll
        for (int j = 0; j < 8; ++j) {
            const int g = g0 + j;
            const int a = g - (NT3 + NT2);
            out8[g] = pack_h4(U1_0[a] * w10, U1_1[a] * w11,
                              U1_1[16 + a] * w11, U1_1[32 + a] * w11);
        }
    }
}

// ---- node loop (R6 geometry): 128 thr, 2 nodes/thread packed float2 in LDS,
// fp16 coef table in LDS (b64 broadcast) consumed via v_fma_mix-style scalar
// FMAs: fmaf(__half2float(h), x, acc) — fpext folds into the FMA operand.
__global__ __launch_bounds__(128) void sc_apply(
    const float* __restrict__ xg, const float* __restrict__ ws,
    float* __restrict__ outg)
{
    const int c = blockIdx.x, e = blockIdx.y, tid = threadIdx.x;
    __shared__ uint2 Tsh[NTT];     // 7744 B fp16 table
    __shared__ v2f xs[16 * 128];   // 16384 B: row i, (node0,node1) pair per thread

    const uint2* __restrict__ tG =
        (const uint2*)(ws + TALL2F) + (size_t)(e * CN + c) * NTT;
    for (int i = tid; i < NTT; i += 128) Tsh[i] = tG[i];

    const int* lists = (const int*)ws + e * BN;
    const int cnt = ((const int*)ws)[EN * BN + e];
    __syncthreads();

    for (int base = 0; base < cnt; base += 256) {
        const int s0 = base + tid, s1 = base + tid + 128;
        const bool act0 = s0 < cnt, act1 = s1 < cnt;
        const int n0 = lists[act0 ? s0 : 0];
        const int n1 = lists[act1 ? s1 : 0];
        const float4* p0 = (const float4*)(xg + ((size_t)n0 * CN + c) * 16);
        const float4* p1 = (const float4*)(xg + ((size_t)n1 * CN + c) * 16);
#pragma unroll
        for (int d = 0; d < 4; ++d) {
            const float4 v0 = p0[d]; const float4 v1 = p1[d];
            v2f w;
            w.x = v0.x; w.y = v1.x; xs[(4 * d + 0) * 128 + tid] = w;
            w.x = v0.y; w.y = v1.y; xs[(4 * d + 1) * 128 + tid] = w;
            w.x = v0.z; w.y = v1.z; xs[(4 * d + 2) * 128 + tid] = w;
            w.x = v0.w; w.y = v1.w; xs[(4 * d + 3) * 128 + tid] = w;
        }
        // xs columns are thread-private: no barrier anywhere.

        float acc00 = 0.f, acc01 = 0.f, acc10 = 0.f, acc11 = 0.f;
        float acc20 = 0.f, acc21 = 0.f, acc30 = 0.f, acc31 = 0.f;
        int t3 = 0, t2 = NT3;
#pragma unroll 1
        for (int a = 0; a < 16; ++a) {
            const v2f xa = xs[a * 128 + tid];
            const uint2 t1w = Tsh[NT3 + NT2 + a];
            const __half2 t1A = *reinterpret_cast<const __half2*>(&t1w.x);
            const __half2 t1B = *reinterpret_cast<const __half2*>(&t1w.y);
            float tP00 = __low2float(t1A), tP10 = __high2float(t1A);
            float tP20 = __low2float(t1B), tP30 = __high2float(t1B);
            float tP01 = tP00, tP11 = tP10, tP21 = tP20, tP31 = tP30;
#pragma unroll 1
            for (int b = a; b < 16; ++b) {
                const v2f xb = xs[b * 128 + tid];
                const uint2 c2w = Tsh[t2]; ++t2;
                const __half2 c2A = *reinterpret_cast<const __half2*>(&c2w.x);
                const __half2 c2B = *reinterpret_cast<const __half2*>(&c2w.y);
                float tB00 = __low2float(c2A), tB10 = __high2float(c2A);
                float tB20 = __low2float(c2B), tB30 = __high2float(c2B);
                float tB01 = tB00, tB11 = tB10, tB21 = tB20, tB31 = tB30;
#pragma unroll 4
                for (int cc = b; cc < 16; ++cc) {
                    const v2f xc = xs[cc * 128 + tid];
                    const uint2 w = Tsh[t3]; ++t3;
                    const __half2 hA = *reinterpret_cast<const __half2*>(&w.x);
                    const __half2 hB = *reinterpret_cast<const __half2*>(&w.y);
                    tB00 = fmaf(__low2float(hA),  xc.x, tB00);
                    tB01 = fmaf(__low2float(hA),  xc.y, tB01);
                    tB10 = fmaf(__high2float(hA), xc.x, tB10);
                    tB11 = fmaf(__high2float(hA), xc.y, tB11);
                    tB20 = fmaf(__low2float(hB),  xc.x, tB20);
                    tB21 = fmaf(__low2float(hB),  xc.y, tB21);
                    tB30 = fmaf(__high2float(hB), xc.x, tB30);
                    tB31 = fmaf(__high2float(hB), xc.y, tB31);
                }
                tP00 = fmaf(tB00, xb.x, tP00); tP01 = fmaf(tB01, xb.y, tP01);
                tP10 = fmaf(tB10, xb.x, tP10); tP11 = fmaf(tB11, xb.y, tP11);
                tP20 = fmaf(tB20, xb.x, tP20); tP21 = fmaf(tB21, xb.y, tP21);
                tP30 = fmaf(tB30, xb.x, tP30); tP31 = fmaf(tB31, xb.y, tP31);
            }
            acc00 = fmaf(tP00, xa.x, acc00); acc01 = fmaf(tP01, xa.y, acc01);
            acc10 = fmaf(tP10, xa.x, acc10); acc11 = fmaf(tP11, xa.y, acc11);
            acc20 = fmaf(tP20, xa.x, acc20); acc21 = fmaf(tP21, xa.y, acc21);
            acc30 = fmaf(tP30, xa.x, acc30); acc31 = fmaf(tP31, xa.y, acc31);
        }
        if (act0) {
            float* o = outg + (size_t)n0 * 512;
            o[c] = acc00;
            o[128 + c * 3 + 0] = acc10; o[128 + c * 3 + 1] = acc20; o[128 + c * 3 + 2] = acc30;
        }
        if (act1) {
            float* o = outg + (size_t)n1 * 512;
            o[c] = acc01;
            o[128 + c * 3 + 0] = acc11; o[128 + c * 3 + 1] = acc21; o[128 + c * 3 + 2] = acc31;
        }
    }
}

// ======================= fallback path (proven, f32) =======================
__global__ __launch_bounds__(256) void prep_sym(
    const float* __restrict__ U3_0, const float* __restrict__ U2_0,
    const float* __restrict__ U3_1, const float* __restrict__ U2_1,
    const float* __restrict__ yg, float* __restrict__ ws)
{
    const int bid = blockIdx.x, tid = threadIdx.x;
    if (bid < PREP_BLOCKS) {
        const int N0 = K3_0*NT3, N1 = 3*K3_1*NT3, P0 = K2_0*NT2;
        const int it = bid*256 + tid;
        if (it >= PREP_TOT) return;
        if (it < N0 + N1) {
            const float* U3; int m, k, K, t, dst;
            if (it < N0) { U3 = U3_0; K = K3_0; m = 0; k = it / NT3; t = it - k*NT3; dst = U3S0_OFF + it; }
            else { int r = it - N0; U3 = U3_1; K = K3_1; int mk = r / NT3; t = r - mk*NT3;
                   m = mk / K3_1; k = mk - m*K3_1; dst = U3S1_OFF + r; }
            int a = 0, rem = t;
            while (rem >= ((16-a)*(17-a))/2) { rem -= ((16-a)*(17-a))/2; ++a; }
            int b = a;
            while (rem >= 16-b) { rem -= 16-b; ++b; }
            const int cc = b + rem;
            #define AT3(i,j,l) U3[(size_t)(((m*16+(i))*16+(j))*16+(l))*K + k]
            float D = AT3(a,b,cc) + AT3(a,cc,b) + AT3(b,a,cc)
                    + AT3(b,cc,a) + AT3(cc,a,b) + AT3(cc,b,a);
            #undef AT3
            const int eq = (a==b) + (b==cc);
            D *= (eq==2) ? (1.f/6.f) : (eq==1) ? 0.5f : 1.f;
            ws[dst] = D;
        } else {
            const int it2 = it - (N0+N1);
            const float* U2; int m, k, K, pr, dst;
            if (it2 < P0) { U2 = U2_0; K = K2_0; m = 0; k = it2 / NT2; pr = it2 - k*NT2; dst = U2S0_OFF + it2; }
            else { int r = it2 - P0; U2 = U2_1; K = K2_1; int mk = r / NT2; pr = r - mk*NT2;
                   m = mk / K2_1; k = mk - m*K2_1; dst = U2S1_OFF + r; }
            int a = 0, rem = pr;
            while (rem >= 16-a) { rem -= 16-a; ++a; }
            const int b = a + rem;
            float D = U2[(size_t)((m*16+a)*16+b)*K + k]
                    + U2[(size_t)((m*16+b)*16+a)*K + k];
            if (a == b) D *= 0.5f;
            ws[dst] = D;
        }
    } else if (bid < PREP_BLOCKS + EN) {
        const int e = bid - PREP_BLOCKS;
        __shared__ int lcnt;
        if (tid == 0) lcnt = 0;
        __syncthreads();
        int* lists = (int*)(ws + LISTS_OFF);
        for (int b = tid; b < BN; b += 256) {
            if (yg[b*EN + e] > 0.5f) {
                int p = atomicAdd(&lcnt, 1);
                lists[e*BN + p] = b;
            }
        }
        __syncthreads();
        if (tid == 0) ((int*)(ws + CNT_OFF))[e] = lcnt;
    }
}

__global__ __launch_bounds__(128) void sc_main_fused(
    const float* __restrict__ xg,
    const float* __restrict__ U1_0, const float* __restrict__ U1_1,
    const float* __restrict__ W3_0, const float* __restrict__ W2_0, const float* __restrict__ W1_0,
    const float* __restrict__ W3_1, const float* __restrict__ W2_1, const float* __restrict__ W1_1,
    const float* __restrict__ ws, float* __restrict__ outg)
{
    const int c = blockIdx.x, e = blockIdx.y, tid = threadIdx.x;
    __shared__ float4 T3s[NT3];
    __shared__ float4 T2s[NT2];
    __shared__ float4 T1s[16];
    __shared__ float xs0[16*128];
    __shared__ float xs1[16*128];
    __shared__ float wk30s[K3_0], wk31s[K3_1], wk20s[K2_0], wk21s[K2_1];

    if (tid < K3_0) wk30s[tid] = W3_0[(e*K3_0 + tid)*CN + c];
    if (tid >= 32 && tid < 32 + K3_1) wk31s[tid-32] = W3_1[(e*K3_1 + (tid-32))*CN + c];
    if (tid >= 72 && tid < 72 + K2_0) wk20s[tid-72] = W2_0[(e*K2_0 + (tid-72))*CN + c];
    if (tid >= 80 && tid < 80 + K2_1) wk21s[tid-80] = W2_1[(e*K2_1 + (tid-80))*CN + c];
    __syncthreads();

    const float* u3s0 = ws + U3S0_OFF;
    const float* u3s1 = ws + U3S1_OFF;
    for (int g = tid; g < NT3/4; g += 128) {
        float4 A0 = make_float4(0,0,0,0), A1 = A0, A2 = A0, A3 = A0;
#pragma unroll
        for (int k = 0; k < K3_0; ++k) {
            const float w = wk30s[k];
            const float4 u = ((const float4*)(u3s0 + k*NT3))[g];
            A0.x = fmaf(u.x, w, A0.x); A0.y = fmaf(u.y, w, A0.y);
            A0.z = fmaf(u.z, w, A0.z); A0.w = fmaf(u.w, w, A0.w);
        }
#pragma unroll 8
        for (int k = 0; k < K3_1; ++k) {
            const float w = wk31s[k];
            const float4 ua = ((const float4*)(u3s1 + k*NT3))[g];
            A1.x = fmaf(ua.x, w, A1.x); A1.y = fmaf(ua.y, w, A1.y);
            A1.z = fmaf(ua.z, w, A1.z); A1.w = fmaf(ua.w, w, A1.w);
            const float4 ub = ((const float4*)(u3s1 + (K3_1 + k)*NT3))[g];
            A2.x = fmaf(ub.x, w, A2.x); A2.y = fmaf(ub.y, w, A2.y);
            A2.z = fmaf(ub.z, w, A2.z); A2.w = fmaf(ub.w, w, A2.w);
            const float4 uc = ((const float4*)(u3s1 + (2*K3_1 + k)*NT3))[g];
            A3.x = fmaf(uc.x, w, A3.x); A3.y = fmaf(uc.y, w, A3.y);
            A3.z = fmaf(uc.z, w, A3.z); A3.w = fmaf(uc.w, w, A3.w);
        }
        T3s[4*g+0] = make_float4(A0.x, A1.x, A2.x, A3.x);
        T3s[4*g+1] = make_float4(A0.y, A1.y, A2.y, A3.y);
        T3s[4*g+2] = make_float4(A0.z, A1.z, A2.z, A3.z);
        T3s[4*g+3] = make_float4(A0.w, A1.w, A2.w, A3.w);
    }
    const float* u2s0 = ws + U2S0_OFF;
    const float* u2s1 = ws + U2S1_OFF;
    for (int g = tid; g < NT2/4; g += 128) {
        float4 A0 = make_float4(0,0,0,0), A1 = A0, A2 = A0, A3 = A0;
#pragma unroll
        for (int k = 0; k < K2_0; ++k) {
            const float w = wk20s[k];
            const float4 u = ((const float4*)(u2s0 + k*NT2))[g];
            A0.x = fmaf(u.x, w, A0.x); A0.y = fmaf(u.y, w, A0.y);
            A0.z = fmaf(u.z, w, A0.z); A0.w = fmaf(u.w, w, A0.w);
        }
#pragma unroll
        for (int k = 0; k < K2_1; ++k) {
            const float w = wk21s[k];
            const float4 ua = ((const float4*)(u2s1 + k*NT2))[g];
            A1.x = fmaf(ua.x, w, A1.x); A1.y = fmaf(ua.y, w, A1.y);
            A1.z = fmaf(ua.z, w, A1.z); A1.w = fmaf(ua.w, w, A1.w);
            const float4 ub = ((const float4*)(u2s1 + (K2_1 + k)*NT2))[g];
            A2.x = fmaf(ub.x, w, A2.x); A2.y = fmaf(ub.y, w, A2.y);
            A2.z = fmaf(ub.z, w, A2.z); A2.w = fmaf(ub.w, w, A2.w);
            const float4 uc = ((const float4*)(u2s1 + (2*K2_1 + k)*NT2))[g];
            A3.x = fmaf(uc.x, w, A3.x); A3.y = fmaf(uc.y, w, A3.y);
            A3.z = fmaf(uc.z, w, A3.z); A3.w = fmaf(uc.w, w, A3.w);
        }
        T2s[4*g+0] = make_float4(A0.x, A1.x, A2.x, A3.x);
        T2s[4*g+1] = make_float4(A0.y, A1.y, A2.y, A3.y);
        T2s[4*g+2] = make_float4(A0.z, A1.z, A2.z, A3.z);
        T2s[4*g+3] = make_float4(A0.w, A1.w, A2.w, A3.w);
    }
    if (tid < 16) {
        const float wk10 = W1_0[e*CN + c];
        const float wk11 = W1_1[e*CN + c];
        const int j = tid;
        T1s[j] = make_float4(U1_0[j]*wk10, U1_1[j]*wk11,
                             U1_1[16+j]*wk11, U1_1[32+j]*wk11);
    }

    const int* lists = (const int*)(ws + LISTS_OFF) + e*BN;
    const int cnt = ((const int*)(ws + CNT_OFF))[e];
    __syncthreads();

    for (int base = 0; base < cnt; base += 256) {
        const int s0 = base + tid, s1 = base + tid + 128;
        const bool act0 = s0 < cnt, act1 = s1 < cnt;
        const int n0 = lists[act0 ? s0 : 0];
        const int n1 = lists[act1 ? s1 : 0];
        const float4* p0 = (const float4*)(xg + ((size_t)n0*CN + c)*16);
        const float4* p1 = (const float4*)(xg + ((size_t)n1*CN + c)*16);
#pragma unroll
        for (int d = 0; d < 4; ++d) {
            const float4 v0 = p0[d]; const float4 v1 = p1[d];
            xs0[(4*d+0)*128+tid] = v0.x; xs0[(4*d+1)*128+tid] = v0.y;
            xs0[(4*d+2)*128+tid] = v0.z; xs0[(4*d+3)*128+tid] = v0.w;
            xs1[(4*d+0)*128+tid] = v1.x; xs1[(4*d+1)*128+tid] = v1.y;
            xs1[(4*d+2)*128+tid] = v1.z; xs1[(4*d+3)*128+tid] = v1.w;
        }
        float4 acc0 = make_float4(0,0,0,0), acc1 = acc0;
        int t3 = 0, t2i = 0;
#pragma unroll 1
        for (int a = 0; a < 16; ++a) {
            const float xa0 = xs0[a*128+tid];
            const float xa1 = xs1[a*128+tid];
            float4 tP0 = T1s[a], tP1 = tP0;
#pragma unroll 1
            for (int b = a; b < 16; ++b) {
                const float xb0 = xs0[b*128+tid];
                const float xb1 = xs1[b*128+tid];
                const float4 c2v = T2s[t2i]; ++t2i;
                float4 tB0 = c2v, tB1 = c2v;
#pragma unroll 4
                for (int cc = b; cc < 16; ++cc) {
                    const float xc0 = xs0[cc*128+tid];
                    const float xc1 = xs1[cc*128+tid];
                    const float4 c3v = T3s[t3]; ++t3;
                    tB0.x = fmaf(c3v.x, xc0, tB0.x); tB0.y = fmaf(c3v.y, xc0, tB0.y);
                    tB0.z = fmaf(c3v.z, xc0, tB0.z); tB0.w = fmaf(c3v.w, xc0, tB0.w);
                    tB1.x = fmaf(c3v.x, xc1, tB1.x); tB1.y = fmaf(c3v.y, xc1, tB1.y);
                    tB1.z = fmaf(c3v.z, xc1, tB1.z); tB1.w = fmaf(c3v.w, xc1, tB1.w);
                }
                tP0.x = fmaf(tB0.x, xb0, tP0.x); tP0.y = fmaf(tB0.y, xb0, tP0.y);
                tP0.z = fmaf(tB0.z, xb0, tP0.z); tP0.w = fmaf(tB0.w, xb0, tP0.w);
                tP1.x = fmaf(tB1.x, xb1, tP1.x); tP1.y = fmaf(tB1.y, xb1, tP1.y);
                tP1.z = fmaf(tB1.z, xb1, tP1.z); tP1.w = fmaf(tB1.w, xb1, tP1.w);
            }
            acc0.x = fmaf(tP0.x, xa0, acc0.x); acc0.y = fmaf(tP0.y, xa0, acc0.y);
            acc0.z = fmaf(tP0.z, xa0, acc0.z); acc0.w = fmaf(tP0.w, xa0, acc0.w);
            acc1.x = fmaf(tP1.x, xa1, acc1.x); acc1.y = fmaf(tP1.y, xa1, acc1.y);
            acc1.z = fmaf(tP1.z, xa1, acc1.z); acc1.w = fmaf(tP1.w, xa1, acc1.w);
        }
        if (act0) {
            float* o = outg + (size_t)n0*512;
            o[c] = acc0.x;
            o[128 + c*3 + 0] = acc0.y; o[128 + c*3 + 1] = acc0.z; o[128 + c*3 + 2] = acc0.w;
        }
        if (act1) {
            float* o = outg + (size_t)n1*512;
            o[c] = acc1.x;
            o[128 + c*3 + 0] = acc1.y; o[128 + c*3 + 1] = acc1.z; o[128 + c*3 + 2] = acc1.w;
        }
    }
}

extern "C" void kernel_launch(void* const* d_in, const int* in_sizes, int n_in,
                              void* d_out, int out_size, void* d_ws, size_t ws_size,
                              hipStream_t stream) {
    const float* x = (const float*)d_in[0];
    const float* y = (const float*)d_in[1];
    const float* U3_0 = (const float*)d_in[2];
    const float* U2_0 = (const float*)d_in[3];
    const float* U1_0 = (const float*)d_in[4];
    const float* W3_0 = (const float*)d_in[5];
    const float* W2_0 = (const float*)d_in[6];
    const float* W1_0 = (const float*)d_in[7];
    const float* U3_1 = (const float*)d_in[8];
    const float* U2_1 = (const float*)d_in[9];
    const float* U1_1 = (const float*)d_in[10];
    const float* W3_1 = (const float*)d_in[11];
    const float* W2_1 = (const float*)d_in[12];
    const float* W1_1 = (const float*)d_in[13];
    float* out = (float*)d_out;
    float* ws = (float*)d_ws;

    if (ws_size >= WS2_NEED_BYTES) {
        build_fused<<<dim3(122, EN), 128, 0, stream>>>(
            U3_0, U2_0, U1_0, U3_1, U2_1, U1_1,
            W3_0, W2_0, W1_0, W3_1, W2_1, W1_1, y, ws);
        sc_apply<<<dim3(CN, EN), 128, 0, stream>>>(x, ws, out);
    } else {
        prep_sym<<<dim3(PREP_BLOCKS + EN), 256, 0, stream>>>(U3_0, U2_0, U3_1, U2_1, y, ws);
        sc_main_fused<<<dim3(CN, EN), 128, 0, stream>>>(x, U1_0, U1_1,
                                                        W3_0, W2_0, W1_0,
                                                        W3_1, W2_1, W1_1, ws, out);
    }
}

// Round 10
// 192.868 us; speedup vs baseline: 1.5337x; 1.5337x over previous
//
#include <hip/hip_runtime.h>
#include <stdint.h>

// SymmetricContraction (MACE) on MI355X — symmetrized monomials, 2-kernel design.
//
// out[b,c,m] = sum_{a<=b<=cc} x_a x_b x_cc*T3 + sum_{a<=b} x_a x_b*T2 + sum_a x_a*T1
// Horner: out = sum_a x_a*( T1[a] + sum_{b>=a} x_b*( T2[ab] + sum_{cc>=b} x_cc*T3 ) )
// Irreps fused into float4 slots (0e | 1o m=0..2), all f32 (absmax 0.03125 proven).
//
// R10 (ledger across R0-R9): the global-table architecture (build kernel ->
// 10-20MB ws table -> apply kernel) carries a stable ~115us floor regardless
// of build structure; R0 (table-free) had floor ~0. There are exactly 1280
// (c,e) blocks and the table is per-(c,e) -> each block builds its OWN table
// in LDS (R2's shape) with the register-lean scalar build that R2 lacked:
//  - phase A: lane-per-g coalesced reads of k-major sym-U (L2-resident 400KB),
//    weights are block-uniform -> scalarized to SGPR, 4 scalar f32 accs.
//    VGPR stays low (R2's float4x4 tiling hit 256 VGPR / 9.8% occupancy).
//  - phase B: R6's proven apply loop verbatim (75.5us measured): f32 table
//    b128 broadcast + x as float2 pairs (one ds_read_b64 for 2 nodes) +
//    v_pk_fma_f32 math. One barrier total.
// prep_sym (410 blocks) symmetrizes U3/U2 into ws (k-major) + node lists.

#define BN 2048
#define CN 128
#define EN 10

#define NT3 816   // #sorted triples a<=b<=cc in [0,16)
#define NT2 136   // #sorted pairs a<=b
#define NTT (NT3 + NT2 + 16)   // 968 fused table entries
#define K3_0 23
#define K3_1 33
#define K2_0 4
#define K2_1 5

// ws layout (float offsets) — ~490 KB total
#define U3S0_OFF 0                          // [23][816]
#define U3S1_OFF (K3_0*NT3)                 // [3*33][816]
#define U2S0_OFF (U3S1_OFF + 3*K3_1*NT3)    // [4][136]
#define U2S1_OFF (U2S0_OFF + K2_0*NT2)      // [3*5][136]
#define LISTS_OFF (U2S1_OFF + 3*K2_1*NT2)   // int[10][2048]
#define CNT_OFF (LISTS_OFF + EN*BN)         // int[10]

#define PREP_TOT (K3_0*NT3 + 3*K3_1*NT3 + K2_0*NT2 + 3*K2_1*NT2)  // 102136
#define PREP_BLOCKS ((PREP_TOT + 255) / 256)                       // 400

typedef float v2f __attribute__((ext_vector_type(2)));
#define FMA2(a, b, c) __builtin_elementwise_fma((a), (b), (c))
static __device__ __forceinline__ v2f splat2(float v) { v2f r; r.x = v; r.y = v; return r; }

__global__ __launch_bounds__(256) void prep_sym(
    const float* __restrict__ U3_0, const float* __restrict__ U2_0,
    const float* __restrict__ U3_1, const float* __restrict__ U2_1,
    const float* __restrict__ yg, float* __restrict__ ws)
{
    const int bid = blockIdx.x, tid = threadIdx.x;
    if (bid < PREP_BLOCKS) {
        const int N0 = K3_0*NT3, N1 = 3*K3_1*NT3, P0 = K2_0*NT2;
        const int it = bid*256 + tid;
        if (it >= PREP_TOT) return;
        if (it < N0 + N1) {
            const float* U3; int m, k, K, t, dst;
            if (it < N0) { U3 = U3_0; K = K3_0; m = 0; k = it / NT3; t = it - k*NT3; dst = U3S0_OFF + it; }
            else { int r = it - N0; U3 = U3_1; K = K3_1; int mk = r / NT3; t = r - mk*NT3;
                   m = mk / K3_1; k = mk - m*K3_1; dst = U3S1_OFF + r; }
            // unrank t -> (a<=b<=cc), lexicographic (matches sc_fused loop order)
            int a = 0, rem = t;
            while (rem >= ((16-a)*(17-a))/2) { rem -= ((16-a)*(17-a))/2; ++a; }
            int b = a;
            while (rem >= 16-b) { rem -= 16-b; ++b; }
            const int cc = b + rem;
            #define AT3(i,j,l) U3[(size_t)(((m*16+(i))*16+(j))*16+(l))*K + k]
            float D = AT3(a,b,cc) + AT3(a,cc,b) + AT3(b,a,cc)
                    + AT3(b,cc,a) + AT3(cc,a,b) + AT3(cc,b,a);
            #undef AT3
            const int eq = (a==b) + (b==cc);
            D *= (eq==2) ? (1.f/6.f) : (eq==1) ? 0.5f : 1.f;
            ws[dst] = D;
        } else {
            const int it2 = it - (N0+N1);
            const float* U2; int m, k, K, pr, dst;
            if (it2 < P0) { U2 = U2_0; K = K2_0; m = 0; k = it2 / NT2; pr = it2 - k*NT2; dst = U2S0_OFF + it2; }
            else { int r = it2 - P0; U2 = U2_1; K = K2_1; int mk = r / NT2; pr = r - mk*NT2;
                   m = mk / K2_1; k = mk - m*K2_1; dst = U2S1_OFF + r; }
            int a = 0, rem = pr;
            while (rem >= 16-a) { rem -= 16-a; ++a; }
            const int b = a + rem;
            float D = U2[(size_t)((m*16+a)*16+b)*K + k]
                    + U2[(size_t)((m*16+b)*16+a)*K + k];
            if (a == b) D *= 0.5f;
            ws[dst] = D;
        }
    } else if (bid < PREP_BLOCKS + EN) {
        const int e = bid - PREP_BLOCKS;
        __shared__ int lcnt;
        if (tid == 0) lcnt = 0;
        __syncthreads();
        int* lists = (int*)(ws + LISTS_OFF);
        for (int b = tid; b < BN; b += 256) {
            if (yg[b*EN + e] > 0.5f) {
                int p = atomicAdd(&lcnt, 1);
                lists[e*BN + p] = b;
            }
        }
        __syncthreads();
        if (tid == 0) ((int*)(ws + CNT_OFF))[e] = lcnt;
    }
}

// ---- fused: per-(c,e) block builds its table in LDS, then runs the node loop
__global__ __launch_bounds__(128) void sc_fused(
    const float* __restrict__ xg, const float* __restrict__ ws,
    const float* __restrict__ U1_0, const float* __restrict__ U1_1,
    const float* __restrict__ W3_0, const float* __restrict__ W2_0, const float* __restrict__ W1_0,
    const float* __restrict__ W3_1, const float* __restrict__ W2_1, const float* __restrict__ W1_1,
    float* __restrict__ outg)
{
    const int c = blockIdx.x, e = blockIdx.y, tid = threadIdx.x;
    __shared__ float4 Ts[NTT];     // 15488 B f32 fused table
    __shared__ v2f xs[16 * 128];   // 16384 B: row i, (node0,node1) pair per thread

    // ---- phase A: build table into LDS ----
    // weights: block-uniform addresses (c,e from blockIdx) -> scalarized loads
    {
        float w30[K3_0], w31[K3_1];
#pragma unroll
        for (int k = 0; k < K3_0; ++k) w30[k] = W3_0[(e*K3_0 + k)*CN + c];
#pragma unroll
        for (int k = 0; k < K3_1; ++k) w31[k] = W3_1[(e*K3_1 + k)*CN + c];
        const float* u0 = ws + U3S0_OFF;
        const float* u1 = ws + U3S1_OFF;
#pragma unroll 1
        for (int g = tid; g < NT3; g += 128) {
            float a0 = 0.f, a1 = 0.f, a2 = 0.f, a3 = 0.f;
#pragma unroll
            for (int k = 0; k < K3_0; ++k) a0 = fmaf(u0[k*NT3 + g], w30[k], a0);
#pragma unroll
            for (int k = 0; k < K3_1; ++k) {
                const float wv = w31[k];
                a1 = fmaf(u1[k*NT3 + g], wv, a1);
                a2 = fmaf(u1[(K3_1 + k)*NT3 + g], wv, a2);
                a3 = fmaf(u1[(2*K3_1 + k)*NT3 + g], wv, a3);
            }
            Ts[g] = make_float4(a0, a1, a2, a3);
        }
    }
    {
        float w20[K2_0], w21[K2_1];
#pragma unroll
        for (int k = 0; k < K2_0; ++k) w20[k] = W2_0[(e*K2_0 + k)*CN + c];
#pragma unroll
        for (int k = 0; k < K2_1; ++k) w21[k] = W2_1[(e*K2_1 + k)*CN + c];
        const float* u0 = ws + U2S0_OFF;
        const float* u1 = ws + U2S1_OFF;
#pragma unroll 1
        for (int g = tid; g < NT2; g += 128) {
            float a0 = 0.f, a1 = 0.f, a2 = 0.f, a3 = 0.f;
#pragma unroll
            for (int k = 0; k < K2_0; ++k) a0 = fmaf(u0[k*NT2 + g], w20[k], a0);
#pragma unroll
            for (int k = 0; k < K2_1; ++k) {
                const float wv = w21[k];
                a1 = fmaf(u1[k*NT2 + g], wv, a1);
                a2 = fmaf(u1[(K2_1 + k)*NT2 + g], wv, a2);
                a3 = fmaf(u1[(2*K2_1 + k)*NT2 + g], wv, a3);
            }
            Ts[NT3 + g] = make_float4(a0, a1, a2, a3);
        }
    }
    if (tid < 16) {
        const float w10 = W1_0[e*CN + c];
        const float w11 = W1_1[e*CN + c];
        Ts[NT3 + NT2 + tid] = make_float4(U1_0[tid]*w10, U1_1[tid]*w11,
                                          U1_1[16+tid]*w11, U1_1[32+tid]*w11);
    }

    const int* lists = (const int*)(ws + LISTS_OFF) + e*BN;
    const int cnt = ((const int*)(ws + CNT_OFF))[e];
    __syncthreads();   // table ready

    // ---- phase B: node loop (R6's proven structure, 75.5us measured) ----
    for (int base = 0; base < cnt; base += 256) {
        const int s0 = base + tid, s1 = base + tid + 128;
        const bool act0 = s0 < cnt, act1 = s1 < cnt;
        const int n0 = lists[act0 ? s0 : 0];
        const int n1 = lists[act1 ? s1 : 0];
        const float4* p0 = (const float4*)(xg + ((size_t)n0*CN + c)*16);
        const float4* p1 = (const float4*)(xg + ((size_t)n1*CN + c)*16);
#pragma unroll
        for (int d = 0; d < 4; ++d) {
            const float4 v0 = p0[d]; const float4 v1 = p1[d];
            v2f w;
            w.x = v0.x; w.y = v1.x; xs[(4*d+0)*128+tid] = w;
            w.x = v0.y; w.y = v1.y; xs[(4*d+1)*128+tid] = w;
            w.x = v0.z; w.y = v1.z; xs[(4*d+2)*128+tid] = w;
            w.x = v0.w; w.y = v1.w; xs[(4*d+3)*128+tid] = w;
        }
        // xs columns are thread-private: no barrier needed in the node loop.

        v2f acc0 = splat2(0.f), acc1 = acc0, acc2 = acc0, acc3 = acc0;
        int t3 = 0, t2 = NT3;
#pragma unroll 1
        for (int a = 0; a < 16; ++a) {
            const v2f xa = xs[a*128+tid];
            const float4 t1v = Ts[NT3 + NT2 + a];
            v2f tP0 = splat2(t1v.x), tP1 = splat2(t1v.y),
                tP2 = splat2(t1v.z), tP3 = splat2(t1v.w);
#pragma unroll 1
            for (int b = a; b < 16; ++b) {
                const v2f xb = xs[b*128+tid];
                const float4 c2v = Ts[t2]; ++t2;
                v2f tB0 = splat2(c2v.x), tB1 = splat2(c2v.y),
                    tB2 = splat2(c2v.z), tB3 = splat2(c2v.w);
#pragma unroll 4
                for (int cc = b; cc < 16; ++cc) {
                    const v2f xc = xs[cc*128+tid];
                    const float4 c3v = Ts[t3]; ++t3;
                    tB0 = FMA2(splat2(c3v.x), xc, tB0);
                    tB1 = FMA2(splat2(c3v.y), xc, tB1);
                    tB2 = FMA2(splat2(c3v.z), xc, tB2);
                    tB3 = FMA2(splat2(c3v.w), xc, tB3);
                }
                tP0 = FMA2(tB0, xb, tP0);
                tP1 = FMA2(tB1, xb, tP1);
                tP2 = FMA2(tB2, xb, tP2);
                tP3 = FMA2(tB3, xb, tP3);
            }
            acc0 = FMA2(tP0, xa, acc0);
            acc1 = FMA2(tP1, xa, acc1);
            acc2 = FMA2(tP2, xa, acc2);
            acc3 = FMA2(tP3, xa, acc3);
        }
        if (act0) {
            float* o = outg + (size_t)n0*512;
            o[c] = acc0.x;
            o[128 + c*3 + 0] = acc1.x; o[128 + c*3 + 1] = acc2.x; o[128 + c*3 + 2] = acc3.x;
        }
        if (act1) {
            float* o = outg + (size_t)n1*512;
            o[c] = acc0.y;
            o[128 + c*3 + 0] = acc1.y; o[128 + c*3 + 1] = acc2.y; o[128 + c*3 + 2] = acc3.y;
        }
    }
}

extern "C" void kernel_launch(void* const* d_in, const int* in_sizes, int n_in,
                              void* d_out, int out_size, void* d_ws, size_t ws_size,
                              hipStream_t stream) {
    const float* x = (const float*)d_in[0];
    const float* y = (const float*)d_in[1];
    const float* U3_0 = (const float*)d_in[2];
    const float* U2_0 = (const float*)d_in[3];
    const float* U1_0 = (const float*)d_in[4];
    const float* W3_0 = (const float*)d_in[5];
    const float* W2_0 = (const float*)d_in[6];
    const float* W1_0 = (const float*)d_in[7];
    const float* U3_1 = (const float*)d_in[8];
    const float* U2_1 = (const float*)d_in[9];
    const float* U1_1 = (const float*)d_in[10];
    const float* W3_1 = (const float*)d_in[11];
    const float* W2_1 = (const float*)d_in[12];
    const float* W1_1 = (const float*)d_in[13];
    float* out = (float*)d_out;
    float* ws = (float*)d_ws;   // ~490 KB needed

    prep_sym<<<dim3(PREP_BLOCKS + EN), 256, 0, stream>>>(U3_0, U2_0, U3_1, U2_1, y, ws);
    sc_fused<<<dim3(CN, EN), 128, 0, stream>>>(x, ws, U1_0, U1_1,
                                               W3_0, W2_0, W1_0,
                                               W3_1, W2_1, W1_1, out);
}

// Round 11
// 192.522 us; speedup vs baseline: 1.5365x; 1.0018x over previous
//
#include <hip/hip_runtime.h>
#include <hip/hip_cooperative_groups.h>
#include <stdint.h>

namespace cg = cooperative_groups;

// SymmetricContraction (MACE) on MI355X — symmetrized monomials, single
// cooperative kernel.
//
// out[b,c,m] = sum_{a<=b<=cc} x_a x_b x_cc*T3 + sum_{a<=b} x_a x_b*T2 + sum_a x_a*T1
// Horner: out = sum_a x_a*( T1[a] + sum_{b>=a} x_b*( T2[ab] + sum_{cc>=b} x_cc*T3 ) )
// Irreps fused into float4 slots (0e | 1o m=0..2), all f32.
//
// R11: R10's ledger shows ~75us of total time outside sc_fused (prep_sym +
// launch tail OR fixed harness floor). This round fuses EVERYTHING into one
// cooperative launch: phase 0 = symmetrize U3/U2 into ws (1 elem/thread,
// 163k threads) + node lists; grid.sync(); phase A = per-(c,e) table into
// LDS; phase B = R10's proven node loop. 1280 blocks x 128 thr, 31.9KB LDS
// -> exactly 5 blocks/CU co-resident. Fallback: R10's two-kernel path.

#define BN 2048
#define CN 128
#define EN 10

#define NT3 816   // #sorted triples a<=b<=cc in [0,16)
#define NT2 136   // #sorted pairs a<=b
#define NTT (NT3 + NT2 + 16)   // 968 fused table entries
#define K3_0 23
#define K3_1 33
#define K2_0 4
#define K2_1 5

// ws layout (float offsets) — ~490 KB total
#define U3S0_OFF 0                          // [23][816]
#define U3S1_OFF (K3_0*NT3)                 // [3*33][816]
#define U2S0_OFF (U3S1_OFF + 3*K3_1*NT3)    // [4][136]
#define U2S1_OFF (U2S0_OFF + K2_0*NT2)      // [3*5][136]
#define LISTS_OFF (U2S1_OFF + 3*K2_1*NT2)   // int[10][2048]
#define CNT_OFF (LISTS_OFF + EN*BN)         // int[10]
#define WS_NEED_BYTES ((size_t)(CNT_OFF + EN) * 4)

#define PREP_TOT (K3_0*NT3 + 3*K3_1*NT3 + K2_0*NT2 + 3*K2_1*NT2)  // 102136
#define PREP_BLOCKS ((PREP_TOT + 255) / 256)                       // 400

typedef float v2f __attribute__((ext_vector_type(2)));
#define FMA2(a, b, c) __builtin_elementwise_fma((a), (b), (c))
static __device__ __forceinline__ v2f splat2(float v) { v2f r; r.x = v; r.y = v; return r; }

// ---- shared phase-0 body: symmetrize one element (it < PREP_TOT) ----------
static __device__ __forceinline__ void sym_one(
    int it,
    const float* __restrict__ U3_0, const float* __restrict__ U2_0,
    const float* __restrict__ U3_1, const float* __restrict__ U2_1,
    float* __restrict__ ws)
{
    const int N0 = K3_0*NT3, N1 = 3*K3_1*NT3, P0 = K2_0*NT2;
    if (it < N0 + N1) {
        const float* U3; int m, k, K, t, dst;
        if (it < N0) { U3 = U3_0; K = K3_0; m = 0; k = it / NT3; t = it - k*NT3; dst = U3S0_OFF + it; }
        else { int r = it - N0; U3 = U3_1; K = K3_1; int mk = r / NT3; t = r - mk*NT3;
               m = mk / K3_1; k = mk - m*K3_1; dst = U3S1_OFF + r; }
        // unrank t -> (a<=b<=cc), lexicographic (matches apply loop order)
        int a = 0, rem = t;
        while (rem >= ((16-a)*(17-a))/2) { rem -= ((16-a)*(17-a))/2; ++a; }
        int b = a;
        while (rem >= 16-b) { rem -= 16-b; ++b; }
        const int cc = b + rem;
        #define AT3(i,j,l) U3[(size_t)(((m*16+(i))*16+(j))*16+(l))*K + k]
        float D = AT3(a,b,cc) + AT3(a,cc,b) + AT3(b,a,cc)
                + AT3(b,cc,a) + AT3(cc,a,b) + AT3(cc,b,a);
        #undef AT3
        const int eq = (a==b) + (b==cc);
        D *= (eq==2) ? (1.f/6.f) : (eq==1) ? 0.5f : 1.f;
        ws[dst] = D;
    } else {
        const int it2 = it - (N0+N1);
        const float* U2; int m, k, K, pr, dst;
        if (it2 < P0) { U2 = U2_0; K = K2_0; m = 0; k = it2 / NT2; pr = it2 - k*NT2; dst = U2S0_OFF + it2; }
        else { int r = it2 - P0; U2 = U2_1; K = K2_1; int mk = r / NT2; pr = r - mk*NT2;
               m = mk / K2_1; k = mk - m*K2_1; dst = U2S1_OFF + r; }
        int a = 0, rem = pr;
        while (rem >= 16-a) { rem -= 16-a; ++a; }
        const int b = a + rem;
        float D = U2[(size_t)((m*16+a)*16+b)*K + k]
                + U2[(size_t)((m*16+b)*16+a)*K + k];
        if (a == b) D *= 0.5f;
        ws[dst] = D;
    }
}

// ---- phase A+B body (R10's proven sc_fused, verbatim) ---------------------
static __device__ __forceinline__ void build_and_apply(
    const float* __restrict__ xg, const float* __restrict__ ws,
    const float* __restrict__ U1_0, const float* __restrict__ U1_1,
    const float* __restrict__ W3_0, const float* __restrict__ W2_0, const float* __restrict__ W1_0,
    const float* __restrict__ W3_1, const float* __restrict__ W2_1, const float* __restrict__ W1_1,
    float* __restrict__ outg,
    float4* __restrict__ Ts, v2f* __restrict__ xs,
    int c, int e, int tid)
{
    // ---- phase A: build table into LDS ----
    {
        float w30[K3_0], w31[K3_1];
#pragma unroll
        for (int k = 0; k < K3_0; ++k) w30[k] = W3_0[(e*K3_0 + k)*CN + c];
#pragma unroll
        for (int k = 0; k < K3_1; ++k) w31[k] = W3_1[(e*K3_1 + k)*CN + c];
        const float* u0 = ws + U3S0_OFF;
        const float* u1 = ws + U3S1_OFF;
#pragma unroll 1
        for (int g = tid; g < NT3; g += 128) {
            float a0 = 0.f, a1 = 0.f, a2 = 0.f, a3 = 0.f;
#pragma unroll
            for (int k = 0; k < K3_0; ++k) a0 = fmaf(u0[k*NT3 + g], w30[k], a0);
#pragma unroll
            for (int k = 0; k < K3_1; ++k) {
                const float wv = w31[k];
                a1 = fmaf(u1[k*NT3 + g], wv, a1);
                a2 = fmaf(u1[(K3_1 + k)*NT3 + g], wv, a2);
                a3 = fmaf(u1[(2*K3_1 + k)*NT3 + g], wv, a3);
            }
            Ts[g] = make_float4(a0, a1, a2, a3);
        }
    }
    {
        float w20[K2_0], w21[K2_1];
#pragma unroll
        for (int k = 0; k < K2_0; ++k) w20[k] = W2_0[(e*K2_0 + k)*CN + c];
#pragma unroll
        for (int k = 0; k < K2_1; ++k) w21[k] = W2_1[(e*K2_1 + k)*CN + c];
        const float* u0 = ws + U2S0_OFF;
        const float* u1 = ws + U2S1_OFF;
#pragma unroll 1
        for (int g = tid; g < NT2; g += 128) {
            float a0 = 0.f, a1 = 0.f, a2 = 0.f, a3 = 0.f;
#pragma unroll
            for (int k = 0; k < K2_0; ++k) a0 = fmaf(u0[k*NT2 + g], w20[k], a0);
#pragma unroll
            for (int k = 0; k < K2_1; ++k) {
                const float wv = w21[k];
                a1 = fmaf(u1[k*NT2 + g], wv, a1);
                a2 = fmaf(u1[(K2_1 + k)*NT2 + g], wv, a2);
                a3 = fmaf(u1[(2*K2_1 + k)*NT2 + g], wv, a3);
            }
            Ts[NT3 + g] = make_float4(a0, a1, a2, a3);
        }
    }
    if (tid < 16) {
        const float w10 = W1_0[e*CN + c];
        const float w11 = W1_1[e*CN + c];
        Ts[NT3 + NT2 + tid] = make_float4(U1_0[tid]*w10, U1_1[tid]*w11,
                                          U1_1[16+tid]*w11, U1_1[32+tid]*w11);
    }

    const int* lists = (const int*)(ws + LISTS_OFF) + e*BN;
    const int cnt = ((const int*)(ws + CNT_OFF))[e];
    __syncthreads();   // table ready

    // ---- phase B: node loop ----
    for (int base = 0; base < cnt; base += 256) {
        const int s0 = base + tid, s1 = base + tid + 128;
        const bool act0 = s0 < cnt, act1 = s1 < cnt;
        const int n0 = lists[act0 ? s0 : 0];
        const int n1 = lists[act1 ? s1 : 0];
        const float4* p0 = (const float4*)(xg + ((size_t)n0*CN + c)*16);
        const float4* p1 = (const float4*)(xg + ((size_t)n1*CN + c)*16);
#pragma unroll
        for (int d = 0; d < 4; ++d) {
            const float4 v0 = p0[d]; const float4 v1 = p1[d];
            v2f w;
            w.x = v0.x; w.y = v1.x; xs[(4*d+0)*128+tid] = w;
            w.x = v0.y; w.y = v1.y; xs[(4*d+1)*128+tid] = w;
            w.x = v0.z; w.y = v1.z; xs[(4*d+2)*128+tid] = w;
            w.x = v0.w; w.y = v1.w; xs[(4*d+3)*128+tid] = w;
        }
        // xs columns are thread-private: no barrier in the node loop.

        v2f acc0 = splat2(0.f), acc1 = acc0, acc2 = acc0, acc3 = acc0;
        int t3 = 0, t2 = NT3;
#pragma unroll 1
        for (int a = 0; a < 16; ++a) {
            const v2f xa = xs[a*128+tid];
            const float4 t1v = Ts[NT3 + NT2 + a];
            v2f tP0 = splat2(t1v.x), tP1 = splat2(t1v.y),
                tP2 = splat2(t1v.z), tP3 = splat2(t1v.w);
#pragma unroll 1
            for (int b = a; b < 16; ++b) {
                const v2f xb = xs[b*128+tid];
                const float4 c2v = Ts[t2]; ++t2;
                v2f tB0 = splat2(c2v.x), tB1 = splat2(c2v.y),
                    tB2 = splat2(c2v.z), tB3 = splat2(c2v.w);
#pragma unroll 4
                for (int cc = b; cc < 16; ++cc) {
                    const v2f xc = xs[cc*128+tid];
                    const float4 c3v = Ts[t3]; ++t3;
                    tB0 = FMA2(splat2(c3v.x), xc, tB0);
                    tB1 = FMA2(splat2(c3v.y), xc, tB1);
                    tB2 = FMA2(splat2(c3v.z), xc, tB2);
                    tB3 = FMA2(splat2(c3v.w), xc, tB3);
                }
                tP0 = FMA2(tB0, xb, tP0);
                tP1 = FMA2(tB1, xb, tP1);
                tP2 = FMA2(tB2, xb, tP2);
                tP3 = FMA2(tB3, xb, tP3);
            }
            acc0 = FMA2(tP0, xa, acc0);
            acc1 = FMA2(tP1, xa, acc1);
            acc2 = FMA2(tP2, xa, acc2);
            acc3 = FMA2(tP3, xa, acc3);
        }
        if (act0) {
            float* o = outg + (size_t)n0*512;
            o[c] = acc0.x;
            o[128 + c*3 + 0] = acc1.x; o[128 + c*3 + 1] = acc2.x; o[128 + c*3 + 2] = acc3.x;
        }
        if (act1) {
            float* o = outg + (size_t)n1*512;
            o[c] = acc0.y;
            o[128 + c*3 + 0] = acc1.y; o[128 + c*3 + 1] = acc2.y; o[128 + c*3 + 2] = acc3.y;
        }
    }
}

// ---- single cooperative kernel: phase0 -> grid.sync -> phaseA+B -----------
__global__ __launch_bounds__(128) void sc_all(
    const float* __restrict__ xg, float* __restrict__ ws,
    const float* __restrict__ U3_0, const float* __restrict__ U2_0, const float* __restrict__ U1_0,
    const float* __restrict__ U3_1, const float* __restrict__ U2_1, const float* __restrict__ U1_1,
    const float* __restrict__ W3_0, const float* __restrict__ W2_0, const float* __restrict__ W1_0,
    const float* __restrict__ W3_1, const float* __restrict__ W2_1, const float* __restrict__ W1_1,
    const float* __restrict__ yg, float* __restrict__ outg)
{
    const int c = blockIdx.x, e = blockIdx.y, tid = threadIdx.x;
    __shared__ float4 Ts[NTT];     // 15488 B
    __shared__ v2f xs[16 * 128];   // 16384 B
    __shared__ int lcnt;

    // ---- phase 0 ----
    const int gbid = e * CN + c;            // 0..1279
    const int git = gbid * 128 + tid;       // 0..163839 >= PREP_TOT
    if (git < PREP_TOT)
        sym_one(git, U3_0, U2_0, U3_1, U2_1, ws);
    if (gbid >= 1024 && gbid < 1024 + EN) { // these blocks have git > PREP_TOT
        const int e0 = gbid - 1024;
        if (tid == 0) lcnt = 0;
        __syncthreads();
        int* lists = (int*)(ws + LISTS_OFF);
        for (int b = tid; b < BN; b += 128) {
            if (yg[b*EN + e0] > 0.5f) {
                int p = atomicAdd(&lcnt, 1);
                lists[e0*BN + p] = b;
            }
        }
        __syncthreads();
        if (tid == 0) ((int*)(ws + CNT_OFF))[e0] = lcnt;
    }
    __threadfence();          // make ws writes device-visible before barrier
    cg::this_grid().sync();   // all 1280 blocks co-resident (5/CU by LDS)

    // ---- phase A + B (R10 proven) ----
    build_and_apply(xg, ws, U1_0, U1_1, W3_0, W2_0, W1_0,
                    W3_1, W2_1, W1_1, outg, Ts, xs, c, e, tid);
}

// ======================= fallback: R10 two-kernel path =====================
__global__ __launch_bounds__(256) void prep_sym(
    const float* __restrict__ U3_0, const float* __restrict__ U2_0,
    const float* __restrict__ U3_1, const float* __restrict__ U2_1,
    const float* __restrict__ yg, float* __restrict__ ws)
{
    const int bid = blockIdx.x, tid = threadIdx.x;
    if (bid < PREP_BLOCKS) {
        const int it = bid*256 + tid;
        if (it >= PREP_TOT) return;
        sym_one(it, U3_0, U2_0, U3_1, U2_1, ws);
    } else if (bid < PREP_BLOCKS + EN) {
        const int e = bid - PREP_BLOCKS;
        __shared__ int lc;
        if (tid == 0) lc = 0;
        __syncthreads();
        int* lists = (int*)(ws + LISTS_OFF);
        for (int b = tid; b < BN; b += 256) {
            if (yg[b*EN + e] > 0.5f) {
                int p = atomicAdd(&lc, 1);
                lists[e*BN + p] = b;
            }
        }
        __syncthreads();
        if (tid == 0) ((int*)(ws + CNT_OFF))[e] = lc;
    }
}

__global__ __launch_bounds__(128) void sc_fused(
    const float* __restrict__ xg, const float* __restrict__ ws,
    const float* __restrict__ U1_0, const float* __restrict__ U1_1,
    const float* __restrict__ W3_0, const float* __restrict__ W2_0, const float* __restrict__ W1_0,
    const float* __restrict__ W3_1, const float* __restrict__ W2_1, const float* __restrict__ W1_1,
    float* __restrict__ outg)
{
    const int c = blockIdx.x, e = blockIdx.y, tid = threadIdx.x;
    __shared__ float4 Ts[NTT];
    __shared__ v2f xs[16 * 128];
    build_and_apply(xg, ws, U1_0, U1_1, W3_0, W2_0, W1_0,
                    W3_1, W2_1, W1_1, outg, Ts, xs, c, e, tid);
}

extern "C" void kernel_launch(void* const* d_in, const int* in_sizes, int n_in,
                              void* d_out, int out_size, void* d_ws, size_t ws_size,
                              hipStream_t stream) {
    const float* x = (const float*)d_in[0];
    const float* y = (const float*)d_in[1];
    const float* U3_0 = (const float*)d_in[2];
    const float* U2_0 = (const float*)d_in[3];
    const float* U1_0 = (const float*)d_in[4];
    const float* W3_0 = (const float*)d_in[5];
    const float* W2_0 = (const float*)d_in[6];
    const float* W1_0 = (const float*)d_in[7];
    const float* U3_1 = (const float*)d_in[8];
    const float* U2_1 = (const float*)d_in[9];
    const float* U1_1 = (const float*)d_in[10];
    const float* W3_1 = (const float*)d_in[11];
    const float* W2_1 = (const float*)d_in[12];
    const float* W1_1 = (const float*)d_in[13];
    float* out = (float*)d_out;
    float* ws = (float*)d_ws;   // ~490 KB needed

    // one-time capability check (pure host queries — capture-safe, cached)
    static int coop_ok = -1;
    if (coop_ok < 0) {
        int dev = 0;
        hipGetDevice(&dev);
        hipDeviceProp_t prop{};
        hipGetDeviceProperties(&prop, dev);
        int maxb = 0;
        hipError_t qe = hipOccupancyMaxActiveBlocksPerMultiprocessor(
            &maxb, (const void*)sc_all, 128, 0);
        const int need = (CN * EN + prop.multiProcessorCount - 1) /
                         (prop.multiProcessorCount > 0 ? prop.multiProcessorCount : 1);
        coop_ok = (qe == hipSuccess && prop.cooperativeLaunch && maxb >= need) ? 1 : 0;
    }

    if (ws_size >= WS_NEED_BYTES && coop_ok == 1) {
        void* args[] = {
            (void*)&x, (void*)&ws,
            (void*)&U3_0, (void*)&U2_0, (void*)&U1_0,
            (void*)&U3_1, (void*)&U2_1, (void*)&U1_1,
            (void*)&W3_0, (void*)&W2_0, (void*)&W1_0,
            (void*)&W3_1, (void*)&W2_1, (void*)&W1_1,
            (void*)&y, (void*)&out
        };
        hipLaunchCooperativeKernel((void*)sc_all, dim3(CN, EN), dim3(128),
                                   args, 0, stream);
    } else {
        prep_sym<<<dim3(PREP_BLOCKS + EN), 256, 0, stream>>>(U3_0, U2_0, U3_1, U2_1, y, ws);
        sc_fused<<<dim3(CN, EN), 128, 0, stream>>>(x, ws, U1_0, U1_1,
                                                   W3_0, W2_0, W1_0,
                                                   W3_1, W2_1, W1_1, out);
    }
}

// Round 12
// 185.180 us; speedup vs baseline: 1.5974x; 1.0397x over previous
//
#include <hip/hip_runtime.h>
#include <stdint.h>

// SymmetricContraction (MACE) on MI355X — symmetrized monomials, 2-kernel design.
//
// out[b,c,m] = sum_{a<=b<=cc} x_a x_b x_cc*T3 + sum_{a<=b} x_a x_b*T2 + sum_a x_a*T1
// Horner: out = sum_a x_a*( T1[a] + sum_{b>=a} x_b*( T2[ab] + sum_{cc>=b} x_cc*T3 ) )
// Irreps fused into float4 slots (0e | 1o m=0..2), all f32.
//
// R12 (from R11's decisive null): cooperative fusion didn't move the timed
// total -> residual is a fixed floor, not launch overhead. Reverted to the
// R10 two-kernel path. The remaining lever is sc_fused's phase A (~43us vs
// 15us L2-BW floor; 930 scalar b32 U-loads/thread). Now 4 g-entries per
// thread: every U read is a coalesced global_load_dwordx4 (rows 16B-aligned,
// NT3/NT2 divisible by 4), 4x fewer VMEM issues. Weights stay SGPR-uniform;
// #pragma unroll 4 bounds loads-in-flight (VGPR must stay <=204 to keep the
// LDS-bound 5 blocks/CU). Phase B (75us, LDS+VALU jointly saturated) verbatim.

#define BN 2048
#define CN 128
#define EN 10

#define NT3 816   // #sorted triples a<=b<=cc in [0,16)
#define NT2 136   // #sorted pairs a<=b
#define NTT (NT3 + NT2 + 16)   // 968 fused table entries
#define K3_0 23
#define K3_1 33
#define K2_0 4
#define K2_1 5

// ws layout (float offsets) — ~490 KB total
#define U3S0_OFF 0                          // [23][816]
#define U3S1_OFF (K3_0*NT3)                 // [3*33][816]
#define U2S0_OFF (U3S1_OFF + 3*K3_1*NT3)    // [4][136]
#define U2S1_OFF (U2S0_OFF + K2_0*NT2)      // [3*5][136]
#define LISTS_OFF (U2S1_OFF + 3*K2_1*NT2)   // int[10][2048]
#define CNT_OFF (LISTS_OFF + EN*BN)         // int[10]
#define WS_NEED_BYTES ((size_t)(CNT_OFF + EN) * 4)

#define PREP_TOT (K3_0*NT3 + 3*K3_1*NT3 + K2_0*NT2 + 3*K2_1*NT2)  // 102136
#define PREP_BLOCKS ((PREP_TOT + 255) / 256)                       // 400

typedef float v2f __attribute__((ext_vector_type(2)));
#define FMA2(a, b, c) __builtin_elementwise_fma((a), (b), (c))
static __device__ __forceinline__ v2f splat2(float v) { v2f r; r.x = v; r.y = v; return r; }

__global__ __launch_bounds__(256) void prep_sym(
    const float* __restrict__ U3_0, const float* __restrict__ U2_0,
    const float* __restrict__ U3_1, const float* __restrict__ U2_1,
    const float* __restrict__ yg, float* __restrict__ ws)
{
    const int bid = blockIdx.x, tid = threadIdx.x;
    if (bid < PREP_BLOCKS) {
        const int N0 = K3_0*NT3, N1 = 3*K3_1*NT3, P0 = K2_0*NT2;
        const int it = bid*256 + tid;
        if (it >= PREP_TOT) return;
        if (it < N0 + N1) {
            const float* U3; int m, k, K, t, dst;
            if (it < N0) { U3 = U3_0; K = K3_0; m = 0; k = it / NT3; t = it - k*NT3; dst = U3S0_OFF + it; }
            else { int r = it - N0; U3 = U3_1; K = K3_1; int mk = r / NT3; t = r - mk*NT3;
                   m = mk / K3_1; k = mk - m*K3_1; dst = U3S1_OFF + r; }
            // unrank t -> (a<=b<=cc), lexicographic (matches apply loop order)
            int a = 0, rem = t;
            while (rem >= ((16-a)*(17-a))/2) { rem -= ((16-a)*(17-a))/2; ++a; }
            int b = a;
            while (rem >= 16-b) { rem -= 16-b; ++b; }
            const int cc = b + rem;
            #define AT3(i,j,l) U3[(size_t)(((m*16+(i))*16+(j))*16+(l))*K + k]
            float D = AT3(a,b,cc) + AT3(a,cc,b) + AT3(b,a,cc)
                    + AT3(b,cc,a) + AT3(cc,a,b) + AT3(cc,b,a);
            #undef AT3
            const int eq = (a==b) + (b==cc);
            D *= (eq==2) ? (1.f/6.f) : (eq==1) ? 0.5f : 1.f;
            ws[dst] = D;
        } else {
            const int it2 = it - (N0+N1);
            const float* U2; int m, k, K, pr, dst;
            if (it2 < P0) { U2 = U2_0; K = K2_0; m = 0; k = it2 / NT2; pr = it2 - k*NT2; dst = U2S0_OFF + it2; }
            else { int r = it2 - P0; U2 = U2_1; K = K2_1; int mk = r / NT2; pr = r - mk*NT2;
                   m = mk / K2_1; k = mk - m*K2_1; dst = U2S1_OFF + r; }
            int a = 0, rem = pr;
            while (rem >= 16-a) { rem -= 16-a; ++a; }
            const int b = a + rem;
            float D = U2[(size_t)((m*16+a)*16+b)*K + k]
                    + U2[(size_t)((m*16+b)*16+a)*K + k];
            if (a == b) D *= 0.5f;
            ws[dst] = D;
        }
    } else if (bid < PREP_BLOCKS + EN) {
        const int e = bid - PREP_BLOCKS;
        __shared__ int lcnt;
        if (tid == 0) lcnt = 0;
        __syncthreads();
        int* lists = (int*)(ws + LISTS_OFF);
        for (int b = tid; b < BN; b += 256) {
            if (yg[b*EN + e] > 0.5f) {
                int p = atomicAdd(&lcnt, 1);
                lists[e*BN + p] = b;
            }
        }
        __syncthreads();
        if (tid == 0) ((int*)(ws + CNT_OFF))[e] = lcnt;
    }
}

// ---- fused: per-(c,e) block builds its table in LDS (4 g's per thread,
// coalesced dwordx4 U reads), then runs the proven node loop.
__global__ __launch_bounds__(128) void sc_fused(
    const float* __restrict__ xg, const float* __restrict__ ws,
    const float* __restrict__ U1_0, const float* __restrict__ U1_1,
    const float* __restrict__ W3_0, const float* __restrict__ W2_0, const float* __restrict__ W1_0,
    const float* __restrict__ W3_1, const float* __restrict__ W2_1, const float* __restrict__ W1_1,
    float* __restrict__ outg)
{
    const int c = blockIdx.x, e = blockIdx.y, tid = threadIdx.x;
    __shared__ float4 Ts[NTT];     // 15488 B f32 fused table
    __shared__ v2f xs[16 * 128];   // 16384 B: row i, (node0,node1) pair per thread

    // ---- phase A: build table into LDS, quad-of-g per thread ----
    {
        float w30[K3_0], w31[K3_1];
#pragma unroll
        for (int k = 0; k < K3_0; ++k) w30[k] = W3_0[(e*K3_0 + k)*CN + c];
#pragma unroll
        for (int k = 0; k < K3_1; ++k) w31[k] = W3_1[(e*K3_1 + k)*CN + c];
        const float* u0 = ws + U3S0_OFF;
        const float* u1 = ws + U3S1_OFF;
#pragma unroll 1
        for (int q = tid; q < NT3/4; q += 128) {      // 204 quads
            const int g = 4*q;
            float4 A0 = make_float4(0,0,0,0), A1 = A0, A2 = A0, A3 = A0;
#pragma unroll 4
            for (int k = 0; k < K3_0; ++k) {
                const float w = w30[k];
                const float4 u = *(const float4*)(u0 + k*NT3 + g);
                A0.x = fmaf(u.x, w, A0.x); A0.y = fmaf(u.y, w, A0.y);
                A0.z = fmaf(u.z, w, A0.z); A0.w = fmaf(u.w, w, A0.w);
            }
#pragma unroll 4
            for (int k = 0; k < K3_1; ++k) {
                const float w = w31[k];
                const float4 ua = *(const float4*)(u1 + k*NT3 + g);
                const float4 ub = *(const float4*)(u1 + (K3_1 + k)*NT3 + g);
                const float4 uc = *(const float4*)(u1 + (2*K3_1 + k)*NT3 + g);
                A1.x = fmaf(ua.x, w, A1.x); A1.y = fmaf(ua.y, w, A1.y);
                A1.z = fmaf(ua.z, w, A1.z); A1.w = fmaf(ua.w, w, A1.w);
                A2.x = fmaf(ub.x, w, A2.x); A2.y = fmaf(ub.y, w, A2.y);
                A2.z = fmaf(ub.z, w, A2.z); A2.w = fmaf(ub.w, w, A2.w);
                A3.x = fmaf(uc.x, w, A3.x); A3.y = fmaf(uc.y, w, A3.y);
                A3.z = fmaf(uc.z, w, A3.z); A3.w = fmaf(uc.w, w, A3.w);
            }
            Ts[g+0] = make_float4(A0.x, A1.x, A2.x, A3.x);
            Ts[g+1] = make_float4(A0.y, A1.y, A2.y, A3.y);
            Ts[g+2] = make_float4(A0.z, A1.z, A2.z, A3.z);
            Ts[g+3] = make_float4(A0.w, A1.w, A2.w, A3.w);
        }
    }
    {
        float w20[K2_0], w21[K2_1];
#pragma unroll
        for (int k = 0; k < K2_0; ++k) w20[k] = W2_0[(e*K2_0 + k)*CN + c];
#pragma unroll
        for (int k = 0; k < K2_1; ++k) w21[k] = W2_1[(e*K2_1 + k)*CN + c];
        const float* u0 = ws + U2S0_OFF;
        const float* u1 = ws + U2S1_OFF;
        if (tid < NT2/4) {                            // 34 quads
            const int g = 4*tid;
            float4 A0 = make_float4(0,0,0,0), A1 = A0, A2 = A0, A3 = A0;
#pragma unroll
            for (int k = 0; k < K2_0; ++k) {
                const float w = w20[k];
                const float4 u = *(const float4*)(u0 + k*NT2 + g);
                A0.x = fmaf(u.x, w, A0.x); A0.y = fmaf(u.y, w, A0.y);
                A0.z = fmaf(u.z, w, A0.z); A0.w = fmaf(u.w, w, A0.w);
            }
#pragma unroll
            for (int k = 0; k < K2_1; ++k) {
                const float w = w21[k];
                const float4 ua = *(const float4*)(u1 + k*NT2 + g);
                const float4 ub = *(const float4*)(u1 + (K2_1 + k)*NT2 + g);
                const float4 uc = *(const float4*)(u1 + (2*K2_1 + k)*NT2 + g);
                A1.x = fmaf(ua.x, w, A1.x); A1.y = fmaf(ua.y, w, A1.y);
                A1.z = fmaf(ua.z, w, A1.z); A1.w = fmaf(ua.w, w, A1.w);
                A2.x = fmaf(ub.x, w, A2.x); A2.y = fmaf(ub.y, w, A2.y);
                A2.z = fmaf(ub.z, w, A2.z); A2.w = fmaf(ub.w, w, A2.w);
                A3.x = fmaf(uc.x, w, A3.x); A3.y = fmaf(uc.y, w, A3.y);
                A3.z = fmaf(uc.z, w, A3.z); A3.w = fmaf(uc.w, w, A3.w);
            }
            Ts[NT3 + g+0] = make_float4(A0.x, A1.x, A2.x, A3.x);
            Ts[NT3 + g+1] = make_float4(A0.y, A1.y, A2.y, A3.y);
            Ts[NT3 + g+2] = make_float4(A0.z, A1.z, A2.z, A3.z);
            Ts[NT3 + g+3] = make_float4(A0.w, A1.w, A2.w, A3.w);
        }
    }
    if (tid < 16) {
        const float w10 = W1_0[e*CN + c];
        const float w11 = W1_1[e*CN + c];
        Ts[NT3 + NT2 + tid] = make_float4(U1_0[tid]*w10, U1_1[tid]*w11,
                                          U1_1[16+tid]*w11, U1_1[32+tid]*w11);
    }

    const int* lists = (const int*)(ws + LISTS_OFF) + e*BN;
    const int cnt = ((const int*)(ws + CNT_OFF))[e];
    __syncthreads();   // table ready

    // ---- phase B: node loop (proven structure) ----
    for (int base = 0; base < cnt; base += 256) {
        const int s0 = base + tid, s1 = base + tid + 128;
        const bool act0 = s0 < cnt, act1 = s1 < cnt;
        const int n0 = lists[act0 ? s0 : 0];
        const int n1 = lists[act1 ? s1 : 0];
        const float4* p0 = (const float4*)(xg + ((size_t)n0*CN + c)*16);
        const float4* p1 = (const float4*)(xg + ((size_t)n1*CN + c)*16);
#pragma unroll
        for (int d = 0; d < 4; ++d) {
            const float4 v0 = p0[d]; const float4 v1 = p1[d];
            v2f w;
            w.x = v0.x; w.y = v1.x; xs[(4*d+0)*128+tid] = w;
            w.x = v0.y; w.y = v1.y; xs[(4*d+1)*128+tid] = w;
            w.x = v0.z; w.y = v1.z; xs[(4*d+2)*128+tid] = w;
            w.x = v0.w; w.y = v1.w; xs[(4*d+3)*128+tid] = w;
        }
        // xs columns are thread-private: no barrier in the node loop.

        v2f acc0 = splat2(0.f), acc1 = acc0, acc2 = acc0, acc3 = acc0;
        int t3 = 0, t2 = NT3;
#pragma unroll 1
        for (int a = 0; a < 16; ++a) {
            const v2f xa = xs[a*128+tid];
            const float4 t1v = Ts[NT3 + NT2 + a];
            v2f tP0 = splat2(t1v.x), tP1 = splat2(t1v.y),
                tP2 = splat2(t1v.z), tP3 = splat2(t1v.w);
#pragma unroll 1
            for (int b = a; b < 16; ++b) {
                const v2f xb = xs[b*128+tid];
                const float4 c2v = Ts[t2]; ++t2;
                v2f tB0 = splat2(c2v.x), tB1 = splat2(c2v.y),
                    tB2 = splat2(c2v.z), tB3 = splat2(c2v.w);
#pragma unroll 4
                for (int cc = b; cc < 16; ++cc) {
                    const v2f xc = xs[cc*128+tid];
                    const float4 c3v = Ts[t3]; ++t3;
                    tB0 = FMA2(splat2(c3v.x), xc, tB0);
                    tB1 = FMA2(splat2(c3v.y), xc, tB1);
                    tB2 = FMA2(splat2(c3v.z), xc, tB2);
                    tB3 = FMA2(splat2(c3v.w), xc, tB3);
                }
                tP0 = FMA2(tB0, xb, tP0);
                tP1 = FMA2(tB1, xb, tP1);
                tP2 = FMA2(tB2, xb, tP2);
                tP3 = FMA2(tB3, xb, tP3);
            }
            acc0 = FMA2(tP0, xa, acc0);
            acc1 = FMA2(tP1, xa, acc1);
            acc2 = FMA2(tP2, xa, acc2);
            acc3 = FMA2(tP3, xa, acc3);
        }
        if (act0) {
            float* o = outg + (size_t)n0*512;
            o[c] = acc0.x;
            o[128 + c*3 + 0] = acc1.x; o[128 + c*3 + 1] = acc2.x; o[128 + c*3 + 2] = acc3.x;
        }
        if (act1) {
            float* o = outg + (size_t)n1*512;
            o[c] = acc0.y;
            o[128 + c*3 + 0] = acc1.y; o[128 + c*3 + 1] = acc2.y; o[128 + c*3 + 2] = acc3.y;
        }
    }
}

extern "C" void kernel_launch(void* const* d_in, const int* in_sizes, int n_in,
                              void* d_out, int out_size, void* d_ws, size_t ws_size,
                              hipStream_t stream) {
    const float* x = (const float*)d_in[0];
    const float* y = (const float*)d_in[1];
    const float* U3_0 = (const float*)d_in[2];
    const float* U2_0 = (const float*)d_in[3];
    const float* U1_0 = (const float*)d_in[4];
    const float* W3_0 = (const float*)d_in[5];
    const float* W2_0 = (const float*)d_in[6];
    const float* W1_0 = (const float*)d_in[7];
    const float* U3_1 = (const float*)d_in[8];
    const float* U2_1 = (const float*)d_in[9];
    const float* U1_1 = (const float*)d_in[10];
    const float* W3_1 = (const float*)d_in[11];
    const float* W2_1 = (const float*)d_in[12];
    const float* W1_1 = (const float*)d_in[13];
    float* out = (float*)d_out;
    float* ws = (float*)d_ws;   // ~490 KB needed

    prep_sym<<<dim3(PREP_BLOCKS + EN), 256, 0, stream>>>(U3_0, U2_0, U3_1, U2_1, y, ws);
    sc_fused<<<dim3(CN, EN), 128, 0, stream>>>(x, ws, U1_0, U1_1,
                                               W3_0, W2_0, W1_0,
                                               W3_1, W2_1, W1_1, out);
}

// Round 14
// 185.136 us; speedup vs baseline: 1.5978x; 1.0002x over previous
//
#include <hip/hip_runtime.h>
#include <stdint.h>

// SymmetricContraction (MACE) on MI355X — symmetrized monomials, 2-kernel design.
//
// out[b,c,m] = sum_{a<=b<=cc} x_a x_b x_cc*T3 + sum_{a<=b} x_a x_b*T2 + sum_a x_a*T1
// Horner: out = sum_a x_a*( T1[a] + sum_{b>=a} x_b*( T2[ab] + sum_{cc>=b} x_cc*T3 ) )
// Irreps fused into float4 slots (0e | 1o m=0..2), all f32.
//
// R13 resubmit (R13 bench was an infra failure — container died, no data).
// Isolated experiment vs R12: prep_sym lane mapping changed from k-major
// (adjacent lanes gather at stride K*4B -> 64 lines/load, latency-bound) to
// t-major/k-minor (adjacent lanes read adjacent k -> 2-3 contiguous lines
// per wave, wave-uniform unrank loops). ws layout unchanged (k-major, what
// phase A needs); scattered writes are fire-and-forget.
// sc_fused is VERBATIM R12 (proven 105us) so the experiment is clean.

#define BN 2048
#define CN 128
#define EN 10

#define NT3 816   // #sorted triples a<=b<=cc in [0,16)
#define NT2 136   // #sorted pairs a<=b
#define NTT (NT3 + NT2 + 16)   // 968 fused table entries
#define K3_0 23
#define K3_1 33
#define K2_0 4
#define K2_1 5

// ws layout (float offsets) — ~490 KB total
#define U3S0_OFF 0                          // [23][816]
#define U3S1_OFF (K3_0*NT3)                 // [3*33][816]
#define U2S0_OFF (U3S1_OFF + 3*K3_1*NT3)    // [4][136]
#define U2S1_OFF (U2S0_OFF + K2_0*NT2)      // [3*5][136]
#define LISTS_OFF (U2S1_OFF + 3*K2_1*NT2)   // int[10][2048]
#define CNT_OFF (LISTS_OFF + EN*BN)         // int[10]
#define WS_NEED_BYTES ((size_t)(CNT_OFF + EN) * 4)

#define PREP_TOT (K3_0*NT3 + 3*K3_1*NT3 + K2_0*NT2 + 3*K2_1*NT2)  // 102136
#define PREP_BLOCKS ((PREP_TOT + 255) / 256)                       // 400

typedef float v2f __attribute__((ext_vector_type(2)));
#define FMA2(a, b, c) __builtin_elementwise_fma((a), (b), (c))
static __device__ __forceinline__ v2f splat2(float v) { v2f r; r.x = v; r.y = v; return r; }

// unrank lexicographic sorted triple (a<=b<=cc) / pair (a<=b) in [0,16)
static __device__ __forceinline__ void unrank3(int t, int& a, int& b, int& cc) {
    a = 0; int rem = t;
    while (rem >= ((16 - a) * (17 - a)) / 2) { rem -= ((16 - a) * (17 - a)) / 2; ++a; }
    b = a;
    while (rem >= 16 - b) { rem -= 16 - b; ++b; }
    cc = b + rem;
}
static __device__ __forceinline__ void unrank2(int pr, int& a, int& b) {
    a = 0; int rem = pr;
    while (rem >= 16 - a) { rem -= 16 - a; ++a; }
    b = a + rem;
}

__global__ __launch_bounds__(256) void prep_sym(
    const float* __restrict__ U3_0, const float* __restrict__ U2_0,
    const float* __restrict__ U3_1, const float* __restrict__ U2_1,
    const float* __restrict__ yg, float* __restrict__ ws)
{
    const int bid = blockIdx.x, tid = threadIdx.x;
    if (bid < PREP_BLOCKS) {
        const int N0 = K3_0*NT3, N1 = 3*K3_1*NT3, P0 = K2_0*NT2;
        const int it = bid*256 + tid;
        if (it >= PREP_TOT) return;
        // ---- t-major / k-minor lane mapping: adjacent lanes -> adjacent k ----
        if (it < N0) {                       // U3_0: t = it/23, k = it%23
            const int t = it / K3_0, k = it - t * K3_0;
            int a, b, cc; unrank3(t, a, b, cc);
            #define AT(i,j,l) U3_0[(size_t)((((i)*16+(j))*16+(l))) * K3_0 + k]
            float D = AT(a,b,cc) + AT(a,cc,b) + AT(b,a,cc)
                    + AT(b,cc,a) + AT(cc,a,b) + AT(cc,b,a);
            #undef AT
            const int eq = (a==b) + (b==cc);
            D *= (eq==2) ? (1.f/6.f) : (eq==1) ? 0.5f : 1.f;
            ws[U3S0_OFF + k*NT3 + t] = D;
        } else if (it < N0 + N1) {           // U3_1: tm = r/33, k = r%33; t = tm/3, m = tm%3
            const int r = it - N0;
            const int tm = r / K3_1, k = r - tm * K3_1;
            const int t = tm / 3, m = tm - 3 * t;
            int a, b, cc; unrank3(t, a, b, cc);
            #define AT(i,j,l) U3_1[(size_t)(((m*16+(i))*16+(j))*16+(l)) * K3_1 + k]
            float D = AT(a,b,cc) + AT(a,cc,b) + AT(b,a,cc)
                    + AT(b,cc,a) + AT(cc,a,b) + AT(cc,b,a);
            #undef AT
            const int eq = (a==b) + (b==cc);
            D *= (eq==2) ? (1.f/6.f) : (eq==1) ? 0.5f : 1.f;
            ws[U3S1_OFF + (m*K3_1 + k)*NT3 + t] = D;
        } else {
            const int it2 = it - (N0 + N1);
            if (it2 < P0) {                  // U2_0: pr = it2/4, k = it2%4
                const int pr = it2 / K2_0, k = it2 - pr * K2_0;
                int a, b; unrank2(pr, a, b);
                float D = U2_0[(size_t)(a*16 + b) * K2_0 + k]
                        + U2_0[(size_t)(b*16 + a) * K2_0 + k];
                if (a == b) D *= 0.5f;
                ws[U2S0_OFF + k*NT2 + pr] = D;
            } else {                         // U2_1: pm = r/5, k = r%5; pr = pm/3, m = pm%3
                const int r2 = it2 - P0;
                const int pm = r2 / K2_1, k = r2 - pm * K2_1;
                const int pr = pm / 3, m = pm - 3 * pr;
                int a, b; unrank2(pr, a, b);
                float D = U2_1[(size_t)((m*16 + a)*16 + b) * K2_1 + k]
                        + U2_1[(size_t)((m*16 + b)*16 + a) * K2_1 + k];
                if (a == b) D *= 0.5f;
                ws[U2S1_OFF + (m*K2_1 + k)*NT2 + pr] = D;
            }
        }
    } else if (bid < PREP_BLOCKS + EN) {
        const int e = bid - PREP_BLOCKS;
        __shared__ int lcnt;
        if (tid == 0) lcnt = 0;
        __syncthreads();
        int* lists = (int*)(ws + LISTS_OFF);
        for (int b = tid; b < BN; b += 256) {
            if (yg[b*EN + e] > 0.5f) {
                int p = atomicAdd(&lcnt, 1);
                lists[e*BN + p] = b;
            }
        }
        __syncthreads();
        if (tid == 0) ((int*)(ws + CNT_OFF))[e] = lcnt;
    }
}

// ---- fused: per-(c,e) block builds its table in LDS (4 g's per thread,
// coalesced dwordx4 U reads), then runs the proven node loop. (R12 verbatim)
__global__ __launch_bounds__(128) void sc_fused(
    const float* __restrict__ xg, const float* __restrict__ ws,
    const float* __restrict__ U1_0, const float* __restrict__ U1_1,
    const float* __restrict__ W3_0, const float* __restrict__ W2_0, const float* __restrict__ W1_0,
    const float* __restrict__ W3_1, const float* __restrict__ W2_1, const float* __restrict__ W1_1,
    float* __restrict__ outg)
{
    const int c = blockIdx.x, e = blockIdx.y, tid = threadIdx.x;
    __shared__ float4 Ts[NTT];     // 15488 B f32 fused table
    __shared__ v2f xs[16 * 128];   // 16384 B: row i, (node0,node1) pair per thread

    // ---- phase A: build table into LDS, quad-of-g per thread ----
    {
        float w30[K3_0], w31[K3_1];
#pragma unroll
        for (int k = 0; k < K3_0; ++k) w30[k] = W3_0[(e*K3_0 + k)*CN + c];
#pragma unroll
        for (int k = 0; k < K3_1; ++k) w31[k] = W3_1[(e*K3_1 + k)*CN + c];
        const float* u0 = ws + U3S0_OFF;
        const float* u1 = ws + U3S1_OFF;
#pragma unroll 1
        for (int q = tid; q < NT3/4; q += 128) {      // 204 quads
            const int g = 4*q;
            float4 A0 = make_float4(0,0,0,0), A1 = A0, A2 = A0, A3 = A0;
#pragma unroll 4
            for (int k = 0; k < K3_0; ++k) {
                const float w = w30[k];
                const float4 u = *(const float4*)(u0 + k*NT3 + g);
                A0.x = fmaf(u.x, w, A0.x); A0.y = fmaf(u.y, w, A0.y);
                A0.z = fmaf(u.z, w, A0.z); A0.w = fmaf(u.w, w, A0.w);
            }
#pragma unroll 4
            for (int k = 0; k < K3_1; ++k) {
                const float w = w31[k];
                const float4 ua = *(const float4*)(u1 + k*NT3 + g);
                const float4 ub = *(const float4*)(u1 + (K3_1 + k)*NT3 + g);
                const float4 uc = *(const float4*)(u1 + (2*K3_1 + k)*NT3 + g);
                A1.x = fmaf(ua.x, w, A1.x); A1.y = fmaf(ua.y, w, A1.y);
                A1.z = fmaf(ua.z, w, A1.z); A1.w = fmaf(ua.w, w, A1.w);
                A2.x = fmaf(ub.x, w, A2.x); A2.y = fmaf(ub.y, w, A2.y);
                A2.z = fmaf(ub.z, w, A2.z); A2.w = fmaf(ub.w, w, A2.w);
                A3.x = fmaf(uc.x, w, A3.x); A3.y = fmaf(uc.y, w, A3.y);
                A3.z = fmaf(uc.z, w, A3.z); A3.w = fmaf(uc.w, w, A3.w);
            }
            Ts[g+0] = make_float4(A0.x, A1.x, A2.x, A3.x);
            Ts[g+1] = make_float4(A0.y, A1.y, A2.y, A3.y);
            Ts[g+2] = make_float4(A0.z, A1.z, A2.z, A3.z);
            Ts[g+3] = make_float4(A0.w, A1.w, A2.w, A3.w);
        }
    }
    {
        float w20[K2_0], w21[K2_1];
#pragma unroll
        for (int k = 0; k < K2_0; ++k) w20[k] = W2_0[(e*K2_0 + k)*CN + c];
#pragma unroll
        for (int k = 0; k < K2_1; ++k) w21[k] = W2_1[(e*K2_1 + k)*CN + c];
        const float* u0 = ws + U2S0_OFF;
        const float* u1 = ws + U2S1_OFF;
        if (tid < NT2/4) {                            // 34 quads
            const int g = 4*tid;
            float4 A0 = make_float4(0,0,0,0), A1 = A0, A2 = A0, A3 = A0;
#pragma unroll
            for (int k = 0; k < K2_0; ++k) {
                const float w = w20[k];
                const float4 u = *(const float4*)(u0 + k*NT2 + g);
                A0.x = fmaf(u.x, w, A0.x); A0.y = fmaf(u.y, w, A0.y);
                A0.z = fmaf(u.z, w, A0.z); A0.w = fmaf(u.w, w, A0.w);
            }
#pragma unroll
            for (int k = 0; k < K2_1; ++k) {
                const float w = w21[k];
                const float4 ua = *(const float4*)(u1 + k*NT2 + g);
                const float4 ub = *(const float4*)(u1 + (K2_1 + k)*NT2 + g);
                const float4 uc = *(const float4*)(u1 + (2*K2_1 + k)*NT2 + g);
                A1.x = fmaf(ua.x, w, A1.x); A1.y = fmaf(ua.y, w, A1.y);
                A1.z = fmaf(ua.z, w, A1.z); A1.w = fmaf(ua.w, w, A1.w);
                A2.x = fmaf(ub.x, w, A2.x); A2.y = fmaf(ub.y, w, A2.y);
                A2.z = fmaf(ub.z, w, A2.z); A2.w = fmaf(ub.w, w, A2.w);
                A3.x = fmaf(uc.x, w, A3.x); A3.y = fmaf(uc.y, w, A3.y);
                A3.z = fmaf(uc.z, w, A3.z); A3.w = fmaf(uc.w, w, A3.w);
            }
            Ts[NT3 + g+0] = make_float4(A0.x, A1.x, A2.x, A3.x);
            Ts[NT3 + g+1] = make_float4(A0.y, A1.y, A2.y, A3.y);
            Ts[NT3 + g+2] = make_float4(A0.z, A1.z, A2.z, A3.z);
            Ts[NT3 + g+3] = make_float4(A0.w, A1.w, A2.w, A3.w);
        }
    }
    if (tid < 16) {
        const float w10 = W1_0[e*CN + c];
        const float w11 = W1_1[e*CN + c];
        Ts[NT3 + NT2 + tid] = make_float4(U1_0[tid]*w10, U1_1[tid]*w11,
                                          U1_1[16+tid]*w11, U1_1[32+tid]*w11);
    }

    const int* lists = (const int*)(ws + LISTS_OFF) + e*BN;
    const int cnt = ((const int*)(ws + CNT_OFF))[e];
    __syncthreads();   // table ready

    // ---- phase B: node loop (proven structure) ----
    for (int base = 0; base < cnt; base += 256) {
        const int s0 = base + tid, s1 = base + tid + 128;
        const bool act0 = s0 < cnt, act1 = s1 < cnt;
        const int n0 = lists[act0 ? s0 : 0];
        const int n1 = lists[act1 ? s1 : 0];
        const float4* p0 = (const float4*)(xg + ((size_t)n0*CN + c)*16);
        const float4* p1 = (const float4*)(xg + ((size_t)n1*CN + c)*16);
#pragma unroll
        for (int d = 0; d < 4; ++d) {
            const float4 v0 = p0[d]; const float4 v1 = p1[d];
            v2f w;
            w.x = v0.x; w.y = v1.x; xs[(4*d+0)*128+tid] = w;
            w.x = v0.y; w.y = v1.y; xs[(4*d+1)*128+tid] = w;
            w.x = v0.z; w.y = v1.z; xs[(4*d+2)*128+tid] = w;
            w.x = v0.w; w.y = v1.w; xs[(4*d+3)*128+tid] = w;
        }
        // xs columns are thread-private: no barrier in the node loop.

        v2f acc0 = splat2(0.f), acc1 = acc0, acc2 = acc0, acc3 = acc0;
        int t3 = 0, t2 = NT3;
#pragma unroll 1
        for (int a = 0; a < 16; ++a) {
            const v2f xa = xs[a*128+tid];
            const float4 t1v = Ts[NT3 + NT2 + a];
            v2f tP0 = splat2(t1v.x), tP1 = splat2(t1v.y),
                tP2 = splat2(t1v.z), tP3 = splat2(t1v.w);
#pragma unroll 1
            for (int b = a; b < 16; ++b) {
                const v2f xb = xs[b*128+tid];
                const float4 c2v = Ts[t2]; ++t2;
                v2f tB0 = splat2(c2v.x), tB1 = splat2(c2v.y),
                    tB2 = splat2(c2v.z), tB3 = splat2(c2v.w);
#pragma unroll 4
                for (int cc = b; cc < 16; ++cc) {
                    const v2f xc = xs[cc*128+tid];
                    const float4 c3v = Ts[t3]; ++t3;
                    tB0 = FMA2(splat2(c3v.x), xc, tB0);
                    tB1 = FMA2(splat2(c3v.y), xc, tB1);
                    tB2 = FMA2(splat2(c3v.z), xc, tB2);
                    tB3 = FMA2(splat2(c3v.w), xc, tB3);
                }
                tP0 = FMA2(tB0, xb, tP0);
                tP1 = FMA2(tB1, xb, tP1);
                tP2 = FMA2(tB2, xb, tP2);
                tP3 = FMA2(tB3, xb, tP3);
            }
            acc0 = FMA2(tP0, xa, acc0);
            acc1 = FMA2(tP1, xa, acc1);
            acc2 = FMA2(tP2, xa, acc2);
            acc3 = FMA2(tP3, xa, acc3);
        }
        if (act0) {
            float* o = outg + (size_t)n0*512;
            o[c] = acc0.x;
            o[128 + c*3 + 0] = acc1.x; o[128 + c*3 + 1] = acc2.x; o[128 + c*3 + 2] = acc3.x;
        }
        if (act1) {
            float* o = outg + (size_t)n1*512;
            o[c] = acc0.y;
            o[128 + c*3 + 0] = acc1.y; o[128 + c*3 + 1] = acc2.y; o[128 + c*3 + 2] = acc3.y;
        }
    }
}

extern "C" void kernel_launch(void* const* d_in, const int* in_sizes, int n_in,
                              void* d_out, int out_size, void* d_ws, size_t ws_size,
                              hipStream_t stream) {
    const float* x = (const float*)d_in[0];
    const float* y = (const float*)d_in[1];
    const float* U3_0 = (const float*)d_in[2];
    const float* U2_0 = (const float*)d_in[3];
    const float* U1_0 = (const float*)d_in[4];
    const float* W3_0 = (const float*)d_in[5];
    const float* W2_0 = (const float*)d_in[6];
    const float* W1_0 = (const float*)d_in[7];
    const float* U3_1 = (const float*)d_in[8];
    const float* U2_1 = (const float*)d_in[9];
    const float* U1_1 = (const float*)d_in[10];
    const float* W3_1 = (const float*)d_in[11];
    const float* W2_1 = (const float*)d_in[12];
    const float* W1_1 = (const float*)d_in[13];
    float* out = (float*)d_out;
    float* ws = (float*)d_ws;   // ~490 KB needed

    prep_sym<<<dim3(PREP_BLOCKS + EN), 256, 0, stream>>>(U3_0, U2_0, U3_1, U2_1, y, ws);
    sc_fused<<<dim3(CN, EN), 128, 0, stream>>>(x, ws, U1_0, U1_1,
                                               W3_0, W2_0, W1_0,
                                               W3_1, W2_1, W1_1, out);
}